// Round 4
// baseline (269.336 us; speedup 1.0000x reference)
//
#include <hip/hip_runtime.h>
#include <cmath>

#define DIM      128
#define NELEMS   8388608
#define BAND_INT 12288   // key band >= 7.3e-4 dot units; approx err sigma ~7e-6, Bsq spread ~2e-5
#define NBLOCKS  1024

typedef __attribute__((ext_vector_type(8))) short  short8;
typedef __attribute__((ext_vector_type(4))) float  f32x4;

// ws layout (bytes):
//   0      : float Bsq[1024]        (4096)
//   4096   : int   counts[1024]     (4096)
//   8192   : double sse             (8)
//   12288  : int   done             (4)
//   16384  : ushort Ehi[131072]     (262144)   -> end 278528

__device__ inline unsigned short f2bf(float x) {
    unsigned u = __float_as_uint(x);
    unsigned r = u + 0x7FFFu + ((u >> 16) & 1u);   // RNE; inputs finite
    return (unsigned short)(r >> 16);
}

// ---- prep: E -> bf16-hi frags [ct64][kt4][lane64][j8] + Bsq (bit-identical tree) + zero ----
__global__ __launch_bounds__(256) void vq_prep_kernel(
        const float* __restrict__ e, unsigned short* __restrict__ Ehi,
        float* __restrict__ Bsq, int* __restrict__ counts, double* __restrict__ sse,
        int* __restrict__ done) {
    const int tid = threadIdx.x;
    {
        const int t  = blockIdx.x * 256 + tid;   // 0..16383
        const int c  = t >> 4;
        const int gs = t & 15;
        const int kt = gs >> 2, qd = gs & 3;
        const int d0 = gs * 8;
        const float4 v0 = *(const float4*)(e + c * DIM + d0);
        const float4 v1 = *(const float4*)(e + c * DIM + d0 + 4);
        float f[8] = {v0.x, v0.y, v0.z, v0.w, v1.x, v1.y, v1.z, v1.w};
        unsigned short h[8];
        #pragma unroll
        for (int j = 0; j < 8; ++j) h[j] = f2bf(f[j]);
        const int ct = c >> 4, n = c & 15;
        uint4 ph;
        ph.x = h[0] | (h[1] << 16); ph.y = h[2] | (h[3] << 16);
        ph.z = h[4] | (h[5] << 16); ph.w = h[6] | (h[7] << 16);
        *(uint4*)&Ehi[(((ct * 4 + kt) * 64 + qd * 16 + n) * 8)] = ph;
    }
    // Bsq: per-row math bit-identical to round-1 rowsq (float4 squares + 32-lane xor tree)
    {
        const int lane = tid & 31;
        #pragma unroll
        for (int r2 = 0; r2 < 2; ++r2) {
            const int row = blockIdx.x * 16 + (tid >> 5) * 2 + r2;
            const float4 xv = *(const float4*)(e + (size_t)row * DIM + lane * 4);
            float s = xv.x * xv.x + xv.y * xv.y + xv.z * xv.z + xv.w * xv.w;
            #pragma unroll
            for (int off = 16; off > 0; off >>= 1) s += __shfl_xor(s, off);
            if (lane == 0) Bsq[row] = s;
        }
    }
    if (blockIdx.x == 0) {
        ((int4*)counts)[tid] = make_int4(0, 0, 0, 0);
        if (tid == 0) { *sse = 0.0; *done = 0; }
    }
}

// single-ct fragment load: Ehi[ct][kt4][lane64][j8], ct stride = 2048 ushorts
#define LOADCT(BUF, C)                                                          \
    do {                                                                        \
        const unsigned short* _bp = Ehi + (size_t)(C) * 2048;                   \
        _Pragma("unroll")                                                       \
        for (int _kt = 0; _kt < 4; ++_kt)                                       \
            BUF[_kt] = *(const short8*)&_bp[(_kt * 64 + lane) * 8];             \
    } while (0)

// single-ct compute: identical MFMA chain + key/top-2 update order as prior rounds
#define COMPUTECT(BUF, C)                                                       \
    do {                                                                        \
        const int _ct = (C);                                                    \
        f32x4 _a0 = cinit, _a1 = cinit;                                         \
        _Pragma("unroll")                                                       \
        for (int _kt = 0; _kt < 4; ++_kt) {                                     \
            _a0 = __builtin_amdgcn_mfma_f32_16x16x32_bf16(Af[0][_kt], BUF[_kt], _a0, 0, 0, 0); \
            _a1 = __builtin_amdgcn_mfma_f32_16x16x32_bf16(Af[1][_kt], BUF[_kt], _a1, 0, 0, 0); \
        }                                                                       \
        _Pragma("unroll")                                                       \
        for (int _r = 0; _r < 4; ++_r) {                                        \
            const int _k0 = (__float_as_int(_a0[_r]) & (int)0xFFFFFFC0) | _ct;  \
            const int _t0 = min(K1[_r], _k0);                                   \
            K1[_r] = max(K1[_r], _k0);                                          \
            K2[_r] = max(K2[_r], _t0);                                          \
            const int _k1 = (__float_as_int(_a1[_r]) & (int)0xFFFFFFC0) | _ct;  \
            const int _t1 = min(K1[4 + _r], _k1);                               \
            K1[4 + _r] = max(K1[4 + _r], _k1);                                  \
            K2[4 + _r] = max(K2[4 + _r], _t1);                                  \
        }                                                                       \
    } while (0)

// ---- main: barrier-free bf16 MFMA scan + exact verify + fused epilogue + fused finalize ----
// 1024 blocks x 256 thr; block = 64 rows x 1024 codes.
// wave w: rows 32*(w&1)..+31 (2 row-tiles), cts [32*(w>>1), 32*(w>>1)+32).
// Scan uses single-ct double-buffering (BfX/BfY, 16 VGPR each) — R3's ct-pair
// buffers (32 VGPR each) pushed the wave into the >128-reg allocation class
// (2 waves/SIMD, occupancy 19%). NO min-waves clause: (256,4) forced VGPR=64
// and catastrophic spills (R2: WRITE_SIZE 34->229 MB).
__global__ __launch_bounds__(256) void vq_main_kernel(
        const float* __restrict__ x, const float* __restrict__ emb,
        const unsigned short* __restrict__ Ehi, const float* __restrict__ Bsq,
        int* __restrict__ counts, double* __restrict__ sse,
        int* __restrict__ done, float* __restrict__ out) {
    // frag region: [rg4][kt4][lane64][j8] = 8192 ushort (16 KB), then reused as
    // sc: 64 rows x 33 int2 (padded) = 16896 B
    __shared__ __align__(16) unsigned short Xs[8448];
    __shared__ float  sAsq[64];
    __shared__ int    sidx[64];
    __shared__ int    sIsLast;
    __shared__ double red[256];

    const int tid  = threadIdx.x;
    const int wave = tid >> 6;
    const int lane = tid & 63;
    const int n    = lane & 15;
    const int quad = lane >> 4;
    const int row0 = blockIdx.x * 64;

    // ---------- phase 0: stage A-hi frags + bit-exact Asq (round-0 tree, w<2) ----------
    {
        const int rl = tid >> 3, tq = tid & 7;    // rl = row 0..31, 8 threads/row
        const int dbase = tq * 16;
        const int rg_lo = rl >> 4, m = rl & 15;
        #pragma unroll
        for (int w = 0; w < 2; ++w) {
            const int r = 32 * w + rl;
            const float* xp = x + (size_t)(row0 + r) * DIM + dbase;
            float p[4];
            #pragma unroll
            for (int q = 0; q < 4; ++q) {
                const float4 v = *(const float4*)(xp + 4 * q);
                p[q] = v.x * v.x + v.y * v.y + v.z * v.z + v.w * v.w;
                const int dd = dbase + 4 * q;
                const int kt = dd >> 5, qd = (dd >> 3) & 3, j = dd & 7;
                unsigned short h0 = f2bf(v.x), h1 = f2bf(v.y), h2 = f2bf(v.z), h3 = f2bf(v.w);
                uint2 ph;
                ph.x = h0 | (h1 << 16); ph.y = h2 | (h3 << 16);
                const int rg = w * 2 + rg_lo;
                *(uint2*)&Xs[(((rg * 4 + kt) * 64 + qd * 16 + m) * 8) + j] = ph;
            }
            // xor-tree levels identical to prior rounds — bit-exact Asq
            #pragma unroll
            for (int q = 0; q < 4; ++q) p[q] += __shfl_xor(p[q], 4);
            #pragma unroll
            for (int q = 0; q < 4; ++q) p[q] += __shfl_xor(p[q], 2);
            #pragma unroll
            for (int q = 0; q < 4; ++q) p[q] += __shfl_xor(p[q], 1);
            const float s = (p[0] + p[2]) + (p[1] + p[3]);
            if (tq == 0) sAsq[r] = s;
        }
    }
    __syncthreads();

    short8 Af[2][4];     // this wave's 2 row-tiles: rg = 2*(wave&1) + rti
    {
        const int h = wave & 1;
        #pragma unroll
        for (int rti = 0; rti < 2; ++rti)
            #pragma unroll
            for (int kt = 0; kt < 4; ++kt)
                Af[rti][kt] = *(const short8*)&Xs[((((h * 2 + rti) * 4 + kt) * 64 + lane) * 8)];
    }
    __syncthreads();   // all frag reads done before Xs is reused as scratch

    // ---------- phase 1: barrier-free scan, 32 cts per wave, single-ct reg dbuf ----------
    int K1[8], K2[8];
    #pragma unroll
    for (int i = 0; i < 8; ++i) { K1[i] = (int)0x80000000; K2[i] = (int)0x80000000; }

    const f32x4 cinit = {1.0f, 1.0f, 1.0f, 1.0f};   // +1.0 bias -> positive, int-monotone keys

    short8 BfX[4], BfY[4];
    const int c0 = (wave >> 1) * 32;                // ct half; cts ascending, same order as prior rounds
    LOADCT(BfX, c0);
    for (int u = 0; u < 16; ++u) {
        const int cA = c0 + 2 * u, cB = cA + 1;
        LOADCT(BfY, cB);
        COMPUTECT(BfX, cA);
        if (u < 15) LOADCT(BfX, cA + 2);
        COMPUTECT(BfY, cB);
    }

    // ---------- phase 2: key table (top-2 per n per ct-half) + serial exact verify ----------
    int2* sc = (int2*)Xs;   // [64 rows][33 entries]
    #pragma unroll
    for (int r8 = 0; r8 < 8; ++r8) {
        const int lr = 32 * (wave & 1) + 16 * (r8 >> 2) + quad * 4 + (r8 & 3);
        sc[lr * 33 + (wave >> 1) * 16 + n] = make_int2(K1[r8], K2[r8]);
    }
    __syncthreads();

    if (tid < 64) {
        const int row  = tid;
        const int rowg = row0 + row;
        const int2* ent = (const int2*)sc + row * 33;
        int mx = (int)0x80000000;
        #pragma unroll
        for (int e2 = 0; e2 < 32; ++e2) mx = max(mx, ent[e2].x);
        const int thr = mx - BAND_INT;
        int ck[8];
        int nc = 0;
        #pragma unroll
        for (int e2 = 0; e2 < 32; ++e2) {
            const int2 kk = ent[e2];
            const int ne = e2 & 15;
            if (kk.x >= thr && nc < 8) ck[nc++] = ((kk.x & 63) << 4) | ne;
            if (kk.y >= thr && nc < 8) ck[nc++] = ((kk.y & 63) << 4) | ne;
        }
        float bd = INFINITY;
        int   bk = 0x7fffffff;
        const float4* xr = (const float4*)(x + (size_t)rowg * DIM);
        const float   aq = sAsq[row];
        for (int c = 0; c < nc; ++c) {
            const int k = ck[c];
            const float4* er = (const float4*)(emb + (size_t)k * DIM);
            float acc = 0.0f;
            #pragma unroll 4
            for (int dd = 0; dd < 32; ++dd) {   // sequential d order — matches prior rounds / np
                const float4 xv = xr[dd];
                const float4 ev = er[dd];
                acc += xv.x * ev.x;
                acc += xv.y * ev.y;
                acc += xv.z * ev.z;
                acc += xv.w * ev.w;
            }
            const float t    = aq + Bsq[k];
            const float dist = t - 2.0f * acc;
            if (dist < bd || (dist == bd && k < bk)) { bd = dist; bk = k; }
        }
        sidx[row] = bk;
        atomicAdd(&counts[bk], 1);
        float ss = bd;
        #pragma unroll
        for (int off = 32; off > 0; off >>= 1) ss += __shfl_down(ss, off);
        if (tid == 0) atomicAdd(sse, (double)ss);
    }
    __syncthreads();

    // ---------- phase 3: fused gather + STE epilogue (64 rows x 32 float4) ----------
    #pragma unroll
    for (int i = tid; i < 2048; i += 256) {
        const int row = i >> 5, d4 = i & 31;
        const int k = sidx[row];
        const float4 xv = *((const float4*)(x + (size_t)(row0 + row) * DIM) + d4);
        const float4 qv = *((const float4*)emb + (size_t)k * 32 + d4);
        float4 ov;
        ov.x = xv.x + (qv.x - xv.x);
        ov.y = xv.y + (qv.y - xv.y);
        ov.z = xv.z + (qv.z - xv.z);
        ov.w = xv.w + (qv.w - xv.w);
        *((float4*)out + (size_t)(row0 + row) * 32 + d4) = ov;
    }

    // ---------- phase 4: last-block-done fused finalize (loss + perplexity) ----------
    __threadfence();   // release: counts/sse/out writes visible device-wide
    if (tid == 0) sIsLast = (atomicAdd(done, 1) == NBLOCKS - 1);
    __syncthreads();
    if (sIsLast) {
        __threadfence();   // acquire: see all other blocks' counts/sse
        double s = 0.0;
        #pragma unroll
        for (int k = tid; k < 1024; k += 256) {
            const float p = (float)counts[k] * (1.0f / 65536.0f);
            s += (double)p * log((double)p + 1e-10);
        }
        red[tid] = s;
        __syncthreads();
        for (int st = 128; st > 0; st >>= 1) {
            if (tid < st) red[tid] += red[tid + st];
            __syncthreads();
        }
        if (tid == 0) {
            const float m = (float)(*sse * (1.0 / 8388608.0));
            out[NELEMS]     = m + 0.25f * m;
            out[NELEMS + 1] = (float)exp(-red[0]);
        }
    }
}

extern "C" void kernel_launch(void* const* d_in, const int* in_sizes, int n_in,
                              void* d_out, int out_size, void* d_ws, size_t ws_size,
                              hipStream_t stream) {
    const float* x   = (const float*)d_in[0];   // [65536 x 128]
    const float* emb = (const float*)d_in[1];   // [1024 x 128]
    float* out = (float*)d_out;

    char*           ws     = (char*)d_ws;
    float*          Bsq    = (float*)(ws + 0);
    int*            counts = (int*)(ws + 4096);
    double*         sse    = (double*)(ws + 8192);
    int*            done   = (int*)(ws + 12288);
    unsigned short* Ehi    = (unsigned short*)(ws + 16384);

    vq_prep_kernel<<<64, 256, 0, stream>>>(emb, Ehi, Bsq, counts, sse, done);
    vq_main_kernel<<<NBLOCKS, 256, 0, stream>>>(x, emb, Ehi, Bsq, counts, sse, done, out);
}

// Round 5
// 262.489 us; speedup vs baseline: 1.0261x; 1.0261x over previous
//
#include <hip/hip_runtime.h>
#include <cmath>

#define DIM      128
#define NELEMS   8388608
#define BAND_INT 12288   // key band >= 7.3e-4 dot units; approx err sigma ~7e-6, Bsq spread ~2e-5
#define NBLOCKS  1024

typedef __attribute__((ext_vector_type(8))) short  short8;
typedef __attribute__((ext_vector_type(4))) float  f32x4;

// ws layout (bytes):
//   0      : float Bsq[1024]        (4096)
//   4096   : int   counts[1024]     (4096)
//   8192   : double sse             (8)
//   12288  : int   done             (4)
//   16384  : ushort Ehi[131072]     (262144)   -> end 278528

__device__ inline unsigned short f2bf(float x) {
    unsigned u = __float_as_uint(x);
    unsigned r = u + 0x7FFFu + ((u >> 16) & 1u);   // RNE; inputs finite
    return (unsigned short)(r >> 16);
}

// async global->LDS, 16B per lane; LDS dest is wave-uniform base + lane*16
__device__ __forceinline__ void gload_lds16(const void* g, void* l) {
    __builtin_amdgcn_global_load_lds(
        (const __attribute__((address_space(1))) void*)g,
        (__attribute__((address_space(3))) void*)l,
        16, 0, 0);
}

// ---- prep: E -> bf16-hi frags [ct64][kt4][lane64][j8] + Bsq (bit-identical tree) + zero ----
__global__ __launch_bounds__(256) void vq_prep_kernel(
        const float* __restrict__ e, unsigned short* __restrict__ Ehi,
        float* __restrict__ Bsq, int* __restrict__ counts, double* __restrict__ sse,
        int* __restrict__ done) {
    const int tid = threadIdx.x;
    {
        const int t  = blockIdx.x * 256 + tid;   // 0..16383
        const int c  = t >> 4;
        const int gs = t & 15;
        const int kt = gs >> 2, qd = gs & 3;
        const int d0 = gs * 8;
        const float4 v0 = *(const float4*)(e + c * DIM + d0);
        const float4 v1 = *(const float4*)(e + c * DIM + d0 + 4);
        float f[8] = {v0.x, v0.y, v0.z, v0.w, v1.x, v1.y, v1.z, v1.w};
        unsigned short h[8];
        #pragma unroll
        for (int j = 0; j < 8; ++j) h[j] = f2bf(f[j]);
        const int ct = c >> 4, n = c & 15;
        uint4 ph;
        ph.x = h[0] | (h[1] << 16); ph.y = h[2] | (h[3] << 16);
        ph.z = h[4] | (h[5] << 16); ph.w = h[6] | (h[7] << 16);
        *(uint4*)&Ehi[(((ct * 4 + kt) * 64 + qd * 16 + n) * 8)] = ph;
    }
    // Bsq: per-row math bit-identical to round-1 rowsq (float4 squares + 32-lane xor tree)
    {
        const int lane = tid & 31;
        #pragma unroll
        for (int r2 = 0; r2 < 2; ++r2) {
            const int row = blockIdx.x * 16 + (tid >> 5) * 2 + r2;
            const float4 xv = *(const float4*)(e + (size_t)row * DIM + lane * 4);
            float s = xv.x * xv.x + xv.y * xv.y + xv.z * xv.z + xv.w * xv.w;
            #pragma unroll
            for (int off = 16; off > 0; off >>= 1) s += __shfl_xor(s, off);
            if (lane == 0) Bsq[row] = s;
        }
    }
    if (blockIdx.x == 0) {
        ((int4*)counts)[tid] = make_int4(0, 0, 0, 0);
        if (tid == 0) { *sse = 0.0; *done = 0; }
    }
}

// ---- main: LDS-staged shared-B bf16 MFMA scan + exact verify + fused epilogue/finalize ----
// 1024 blocks x 256 thr; block = 64 rows x 1024 codes.
// wave w = row-tile w (rows 16w..16w+15), scans ALL 64 cts -> per-(row,n) key table is
// top-2 over all 64 cts == round-0 semantics exactly (candidates bit-identical).
// B-tiles (2 cts = 8 KB) staged into LDS via global_load_lds, double-buffered, shared
// by all 4 waves: removes the 64-VGPR per-wave B buffers (R0/R3: 2 waves/SIMD,
// latency-exposed scan) and halves Ehi L2 traffic. NO min-waves clause (R2 lesson:
// forcing VGPR=64 spilled 195 MB to scratch).
__global__ __launch_bounds__(256) void vq_main_kernel(
        const float* __restrict__ x, const float* __restrict__ emb,
        const unsigned short* __restrict__ Ehi, const float* __restrict__ Bsq,
        int* __restrict__ counts, double* __restrict__ sse,
        int* __restrict__ done, float* __restrict__ out) {
    // One 16 KB region, three sequential lives:
    //   phase 0: A-hi frags [rg4][kt4][lane64][j8]  (8192 ushort)
    //   scan   : B double-buffer, 2 x (2 cts x 4 KB)
    //   phase 2: sc key table, 64 rows x 17 int2 (8704 B)
    __shared__ __align__(16) unsigned short Xs[8192];
    __shared__ float  sAsq[64];
    __shared__ int    sidx[64];
    __shared__ int    sIsLast;
    __shared__ double red[256];

    const int tid  = threadIdx.x;
    const int wave = tid >> 6;
    const int lane = tid & 63;
    const int n    = lane & 15;
    const int quad = lane >> 4;
    const int row0 = blockIdx.x * 64;

    // ---------- phase 0: stage A-hi frags + bit-exact Asq (prior-round tree) ----------
    {
        const int rl = tid >> 3, tq = tid & 7;    // rl = row 0..31, 8 threads/row
        const int dbase = tq * 16;
        const int rg_lo = rl >> 4, m = rl & 15;
        #pragma unroll
        for (int w = 0; w < 2; ++w) {
            const int r = 32 * w + rl;
            const float* xp = x + (size_t)(row0 + r) * DIM + dbase;
            float p[4];
            #pragma unroll
            for (int q = 0; q < 4; ++q) {
                const float4 v = *(const float4*)(xp + 4 * q);
                p[q] = v.x * v.x + v.y * v.y + v.z * v.z + v.w * v.w;
                const int dd = dbase + 4 * q;
                const int kt = dd >> 5, qd = (dd >> 3) & 3, j = dd & 7;
                unsigned short h0 = f2bf(v.x), h1 = f2bf(v.y), h2 = f2bf(v.z), h3 = f2bf(v.w);
                uint2 ph;
                ph.x = h0 | (h1 << 16); ph.y = h2 | (h3 << 16);
                const int rg = w * 2 + rg_lo;   // == global row >> 4
                *(uint2*)&Xs[(((rg * 4 + kt) * 64 + qd * 16 + m) * 8) + j] = ph;
            }
            // xor-tree levels identical to prior rounds — bit-exact Asq
            #pragma unroll
            for (int q = 0; q < 4; ++q) p[q] += __shfl_xor(p[q], 4);
            #pragma unroll
            for (int q = 0; q < 4; ++q) p[q] += __shfl_xor(p[q], 2);
            #pragma unroll
            for (int q = 0; q < 4; ++q) p[q] += __shfl_xor(p[q], 1);
            const float s = (p[0] + p[2]) + (p[1] + p[3]);
            if (tq == 0) sAsq[r] = s;
        }
    }
    __syncthreads();

    short8 Af[4];        // this wave's single row-tile: rg = wave
    #pragma unroll
    for (int kt = 0; kt < 4; ++kt)
        Af[kt] = *(const short8*)&Xs[(((wave * 4 + kt) * 64 + lane) * 8)];
    __syncthreads();     // all frag reads done before Xs becomes the B staging buffer

    // ---------- phase 1: LDS-staged scan over all 64 cts, 2 cts/tile, dbuf ----------
    int K1[4], K2[4];
    #pragma unroll
    for (int i = 0; i < 4; ++i) { K1[i] = (int)0x80000000; K2[i] = (int)0x80000000; }

    const f32x4 cinit = {1.0f, 1.0f, 1.0f, 1.0f};   // +1.0 bias -> positive, int-monotone keys

    // wave w stages bytes [2048w, 2048w+2048) of each 8 KB tile (2 calls x 1 KB)
    #define STAGE(CUR, IT)                                                               \
        do {                                                                             \
            const char* _g = (const char*)Ehi + (size_t)(IT) * 8192 + wave * 2048 + lane * 16; \
            char*       _l = (char*)Xs + (CUR) * 8192 + wave * 2048;                     \
            gload_lds16(_g, _l);                                                         \
            gload_lds16(_g + 1024, _l + 1024);                                           \
        } while (0)

    int cur = 0;
    STAGE(0, 0);
    __syncthreads();     // drains staging vmcnt; tile 0 visible to all waves
    for (int it = 0; it < 32; ++it) {
        if (it < 31) STAGE(cur ^ 1, it + 1);   // async prefetch next tile
        #pragma unroll
        for (int c = 0; c < 2; ++c) {
            const int ct = 2 * it + c;         // cts ascending 0..63 — same order as R0
            short8 Bf[4];
            #pragma unroll
            for (int kt = 0; kt < 4; ++kt)
                Bf[kt] = *(const short8*)&Xs[(size_t)cur * 4096 + c * 2048 + (kt * 64 + lane) * 8];
            f32x4 a = cinit;
            #pragma unroll
            for (int kt = 0; kt < 4; ++kt)
                a = __builtin_amdgcn_mfma_f32_16x16x32_bf16(Af[kt], Bf[kt], a, 0, 0, 0);
            #pragma unroll
            for (int r = 0; r < 4; ++r) {
                const int k0 = (__float_as_int(a[r]) & (int)0xFFFFFFC0) | ct;
                const int t0 = min(K1[r], k0);
                K1[r] = max(K1[r], k0);
                K2[r] = max(K2[r], t0);
            }
        }
        __syncthreads();   // prefetch landed (vmcnt) + all waves done reading cur (lgkmcnt)
        cur ^= 1;
    }
    #undef STAGE

    // ---------- phase 2: key table (top-2 over all 64 cts per (row,n)) + serial verify ----------
    int2* sc = (int2*)Xs;   // [64 rows][17 entries] (pad +1)
    #pragma unroll
    for (int r = 0; r < 4; ++r) {
        const int lr = wave * 16 + quad * 4 + r;   // C/D row mapping
        sc[lr * 17 + n] = make_int2(K1[r], K2[r]);
    }
    __syncthreads();

    if (tid < 64) {
        const int row  = tid;
        const int rowg = row0 + row;
        const int2* ent = (const int2*)sc + row * 17;
        int mx = (int)0x80000000;
        #pragma unroll
        for (int e2 = 0; e2 < 16; ++e2) mx = max(mx, ent[e2].x);
        const int thr = mx - BAND_INT;
        int ck[8];
        int nc = 0;
        #pragma unroll
        for (int e2 = 0; e2 < 16; ++e2) {
            const int2 kk = ent[e2];
            if (kk.x >= thr && nc < 8) ck[nc++] = ((kk.x & 63) << 4) | e2;
            if (kk.y >= thr && nc < 8) ck[nc++] = ((kk.y & 63) << 4) | e2;
        }
        float bd = INFINITY;
        int   bk = 0x7fffffff;
        const float4* xr = (const float4*)(x + (size_t)rowg * DIM);
        const float   aq = sAsq[row];
        for (int c = 0; c < nc; ++c) {
            const int k = ck[c];
            const float4* er = (const float4*)(emb + (size_t)k * DIM);
            float acc = 0.0f;
            #pragma unroll 4
            for (int dd = 0; dd < 32; ++dd) {   // sequential d order — matches prior rounds / np
                const float4 xv = xr[dd];
                const float4 ev = er[dd];
                acc += xv.x * ev.x;
                acc += xv.y * ev.y;
                acc += xv.z * ev.z;
                acc += xv.w * ev.w;
            }
            const float t    = aq + Bsq[k];
            const float dist = t - 2.0f * acc;
            if (dist < bd || (dist == bd && k < bk)) { bd = dist; bk = k; }
        }
        sidx[row] = bk;
        atomicAdd(&counts[bk], 1);
        float ss = bd;
        #pragma unroll
        for (int off = 32; off > 0; off >>= 1) ss += __shfl_down(ss, off);
        if (tid == 0) atomicAdd(sse, (double)ss);
    }
    __syncthreads();

    // ---------- phase 3: fused gather + STE epilogue (64 rows x 32 float4) ----------
    #pragma unroll
    for (int i = tid; i < 2048; i += 256) {
        const int row = i >> 5, d4 = i & 31;
        const int k = sidx[row];
        const float4 xv = *((const float4*)(x + (size_t)(row0 + row) * DIM) + d4);
        const float4 qv = *((const float4*)emb + (size_t)k * 32 + d4);
        float4 ov;
        ov.x = xv.x + (qv.x - xv.x);
        ov.y = xv.y + (qv.y - xv.y);
        ov.z = xv.z + (qv.z - xv.z);
        ov.w = xv.w + (qv.w - xv.w);
        *((float4*)out + (size_t)(row0 + row) * 32 + d4) = ov;
    }

    // ---------- phase 4: last-block-done fused finalize (loss + perplexity) ----------
    __threadfence();   // release: counts/sse/out writes visible device-wide
    if (tid == 0) sIsLast = (atomicAdd(done, 1) == NBLOCKS - 1);
    __syncthreads();
    if (sIsLast) {
        __threadfence();   // acquire: see all other blocks' counts/sse
        double s = 0.0;
        #pragma unroll
        for (int k = tid; k < 1024; k += 256) {
            const float p = (float)counts[k] * (1.0f / 65536.0f);
            s += (double)p * log((double)p + 1e-10);
        }
        red[tid] = s;
        __syncthreads();
        for (int st = 128; st > 0; st >>= 1) {
            if (tid < st) red[tid] += red[tid + st];
            __syncthreads();
        }
        if (tid == 0) {
            const float m = (float)(*sse * (1.0 / 8388608.0));
            out[NELEMS]     = m + 0.25f * m;
            out[NELEMS + 1] = (float)exp(-red[0]);
        }
    }
}

extern "C" void kernel_launch(void* const* d_in, const int* in_sizes, int n_in,
                              void* d_out, int out_size, void* d_ws, size_t ws_size,
                              hipStream_t stream) {
    const float* x   = (const float*)d_in[0];   // [65536 x 128]
    const float* emb = (const float*)d_in[1];   // [1024 x 128]
    float* out = (float*)d_out;

    char*           ws     = (char*)d_ws;
    float*          Bsq    = (float*)(ws + 0);
    int*            counts = (int*)(ws + 4096);
    double*         sse    = (double*)(ws + 8192);
    int*            done   = (int*)(ws + 12288);
    unsigned short* Ehi    = (unsigned short*)(ws + 16384);

    vq_prep_kernel<<<64, 256, 0, stream>>>(emb, Ehi, Bsq, counts, sse, done);
    vq_main_kernel<<<NBLOCKS, 256, 0, stream>>>(x, emb, Ehi, Bsq, counts, sse, done, out);
}

// Round 6
// 145.657 us; speedup vs baseline: 1.8491x; 1.8021x over previous
//
#include <hip/hip_runtime.h>
#include <cmath>

#define DIM      128
#define NELEMS   8388608
#define BAND_INT 12288   // key band >= 7.3e-4 dot units; approx err sigma ~7e-6, Bsq spread ~2e-5
#define NBLOCKS  1024

typedef __attribute__((ext_vector_type(8))) short  short8;
typedef __attribute__((ext_vector_type(4))) float  f32x4;

// ws layout (bytes):
//   0      : float Bsq[1024]        (4096)
//   4096   : int   counts[1024]     (4096)
//   8192   : double sse             (8)
//   12288  : int   done             (4)
//   16384  : ushort Ehi[131072]     (262144)   -> end 278528

__device__ inline unsigned short f2bf(float x) {
    unsigned u = __float_as_uint(x);
    unsigned r = u + 0x7FFFu + ((u >> 16) & 1u);   // RNE; inputs finite
    return (unsigned short)(r >> 16);
}

// async global->LDS, 16B per lane; LDS dest is wave-uniform base + lane*16
__device__ __forceinline__ void gload_lds16(const void* g, void* l) {
    __builtin_amdgcn_global_load_lds(
        (const __attribute__((address_space(1))) void*)g,
        (__attribute__((address_space(3))) void*)l,
        16, 0, 0);
}

// ---- prep: E -> bf16-hi frags [ct64][kt4][lane64][j8] + Bsq (bit-identical tree) + zero ----
__global__ __launch_bounds__(256) void vq_prep_kernel(
        const float* __restrict__ e, unsigned short* __restrict__ Ehi,
        float* __restrict__ Bsq, int* __restrict__ counts, double* __restrict__ sse,
        int* __restrict__ done) {
    const int tid = threadIdx.x;
    {
        const int t  = blockIdx.x * 256 + tid;   // 0..16383
        const int c  = t >> 4;
        const int gs = t & 15;
        const int kt = gs >> 2, qd = gs & 3;
        const int d0 = gs * 8;
        const float4 v0 = *(const float4*)(e + c * DIM + d0);
        const float4 v1 = *(const float4*)(e + c * DIM + d0 + 4);
        float f[8] = {v0.x, v0.y, v0.z, v0.w, v1.x, v1.y, v1.z, v1.w};
        unsigned short h[8];
        #pragma unroll
        for (int j = 0; j < 8; ++j) h[j] = f2bf(f[j]);
        const int ct = c >> 4, n = c & 15;
        uint4 ph;
        ph.x = h[0] | (h[1] << 16); ph.y = h[2] | (h[3] << 16);
        ph.z = h[4] | (h[5] << 16); ph.w = h[6] | (h[7] << 16);
        *(uint4*)&Ehi[(((ct * 4 + kt) * 64 + qd * 16 + n) * 8)] = ph;
    }
    // Bsq: per-row math bit-identical to round-1 rowsq (float4 squares + 32-lane xor tree)
    {
        const int lane = tid & 31;
        #pragma unroll
        for (int r2 = 0; r2 < 2; ++r2) {
            const int row = blockIdx.x * 16 + (tid >> 5) * 2 + r2;
            const float4 xv = *(const float4*)(e + (size_t)row * DIM + lane * 4);
            float s = xv.x * xv.x + xv.y * xv.y + xv.z * xv.z + xv.w * xv.w;
            #pragma unroll
            for (int off = 16; off > 0; off >>= 1) s += __shfl_xor(s, off);
            if (lane == 0) Bsq[row] = s;
        }
    }
    if (blockIdx.x == 0) {
        ((int4*)counts)[tid] = make_int4(0, 0, 0, 0);
        if (tid == 0) { *sse = 0.0; *done = 0; }
    }
}

// ---- main: LDS-staged shared-B bf16 MFMA scan + exact verify + fused epilogue/finalize ----
// 1024 blocks x 256 thr; block = 64 rows x 1024 codes.
// wave w = row-tile w (rows 16w..16w+15), scans ALL 64 cts -> per-(row,n) key table is
// top-2 over all 64 cts == round-0 semantics exactly (candidates bit-identical).
// B-tiles (2 cts = 8 KB) staged into LDS via global_load_lds, double-buffered, shared
// by all 4 waves. NO min-waves clause (R2 lesson: forcing VGPR=64 spilled 195 MB).
// NO per-block __threadfence(): on gfx94x+ it emits buffer_wbl2+buffer_inv (full
// XCD-L2 writeback+invalidate); 1024 of them kept all 8 L2s perpetually cold and
// dominated R4/R5 (~200 µs at VALUBusy 10%). Ordering is already guaranteed:
// every __syncthreads() drains vmcnt(0) per-wave before s_barrier, so all counts/
// sse atomics are complete at the coherence point before the done-atomic issues.
__global__ __launch_bounds__(256) void vq_main_kernel(
        const float* __restrict__ x, const float* __restrict__ emb,
        const unsigned short* __restrict__ Ehi, const float* __restrict__ Bsq,
        int* __restrict__ counts, double* __restrict__ sse,
        int* __restrict__ done, float* __restrict__ out) {
    // One 16 KB region, three sequential lives:
    //   phase 0: A-hi frags [rg4][kt4][lane64][j8]  (8192 ushort)
    //   scan   : B double-buffer, 2 x (2 cts x 4 KB)
    //   phase 2: sc key table, 64 rows x 17 int2 (8704 B)
    __shared__ __align__(16) unsigned short Xs[8192];
    __shared__ float  sAsq[64];
    __shared__ int    sidx[64];
    __shared__ int    sIsLast;
    __shared__ double red[256];

    const int tid  = threadIdx.x;
    const int wave = tid >> 6;
    const int lane = tid & 63;
    const int n    = lane & 15;
    const int quad = lane >> 4;
    const int row0 = blockIdx.x * 64;

    // ---------- phase 0: stage A-hi frags + bit-exact Asq (prior-round tree) ----------
    {
        const int rl = tid >> 3, tq = tid & 7;    // rl = row 0..31, 8 threads/row
        const int dbase = tq * 16;
        const int rg_lo = rl >> 4, m = rl & 15;
        #pragma unroll
        for (int w = 0; w < 2; ++w) {
            const int r = 32 * w + rl;
            const float* xp = x + (size_t)(row0 + r) * DIM + dbase;
            float p[4];
            #pragma unroll
            for (int q = 0; q < 4; ++q) {
                const float4 v = *(const float4*)(xp + 4 * q);
                p[q] = v.x * v.x + v.y * v.y + v.z * v.z + v.w * v.w;
                const int dd = dbase + 4 * q;
                const int kt = dd >> 5, qd = (dd >> 3) & 3, j = dd & 7;
                unsigned short h0 = f2bf(v.x), h1 = f2bf(v.y), h2 = f2bf(v.z), h3 = f2bf(v.w);
                uint2 ph;
                ph.x = h0 | (h1 << 16); ph.y = h2 | (h3 << 16);
                const int rg = w * 2 + rg_lo;   // == global row >> 4
                *(uint2*)&Xs[(((rg * 4 + kt) * 64 + qd * 16 + m) * 8) + j] = ph;
            }
            // xor-tree levels identical to prior rounds — bit-exact Asq
            #pragma unroll
            for (int q = 0; q < 4; ++q) p[q] += __shfl_xor(p[q], 4);
            #pragma unroll
            for (int q = 0; q < 4; ++q) p[q] += __shfl_xor(p[q], 2);
            #pragma unroll
            for (int q = 0; q < 4; ++q) p[q] += __shfl_xor(p[q], 1);
            const float s = (p[0] + p[2]) + (p[1] + p[3]);
            if (tq == 0) sAsq[r] = s;
        }
    }
    __syncthreads();

    short8 Af[4];        // this wave's single row-tile: rg = wave
    #pragma unroll
    for (int kt = 0; kt < 4; ++kt)
        Af[kt] = *(const short8*)&Xs[(((wave * 4 + kt) * 64 + lane) * 8)];
    __syncthreads();     // all frag reads done before Xs becomes the B staging buffer

    // ---------- phase 1: LDS-staged scan over all 64 cts, 2 cts/tile, dbuf ----------
    int K1[4], K2[4];
    #pragma unroll
    for (int i = 0; i < 4; ++i) { K1[i] = (int)0x80000000; K2[i] = (int)0x80000000; }

    const f32x4 cinit = {1.0f, 1.0f, 1.0f, 1.0f};   // +1.0 bias -> positive, int-monotone keys

    // wave w stages bytes [2048w, 2048w+2048) of each 8 KB tile (2 calls x 1 KB)
    #define STAGE(CUR, IT)                                                               \
        do {                                                                             \
            const char* _g = (const char*)Ehi + (size_t)(IT) * 8192 + wave * 2048 + lane * 16; \
            char*       _l = (char*)Xs + (CUR) * 8192 + wave * 2048;                     \
            gload_lds16(_g, _l);                                                         \
            gload_lds16(_g + 1024, _l + 1024);                                           \
        } while (0)

    int cur = 0;
    STAGE(0, 0);
    __syncthreads();     // drains staging vmcnt; tile 0 visible to all waves
    for (int it = 0; it < 32; ++it) {
        if (it < 31) STAGE(cur ^ 1, it + 1);   // async prefetch next tile
        #pragma unroll
        for (int c = 0; c < 2; ++c) {
            const int ct = 2 * it + c;         // cts ascending 0..63 — same order as R0
            short8 Bf[4];
            #pragma unroll
            for (int kt = 0; kt < 4; ++kt)
                Bf[kt] = *(const short8*)&Xs[(size_t)cur * 4096 + c * 2048 + (kt * 64 + lane) * 8];
            f32x4 a = cinit;
            #pragma unroll
            for (int kt = 0; kt < 4; ++kt)
                a = __builtin_amdgcn_mfma_f32_16x16x32_bf16(Af[kt], Bf[kt], a, 0, 0, 0);
            #pragma unroll
            for (int r = 0; r < 4; ++r) {
                const int k0 = (__float_as_int(a[r]) & (int)0xFFFFFFC0) | ct;
                const int t0 = min(K1[r], k0);
                K1[r] = max(K1[r], k0);
                K2[r] = max(K2[r], t0);
            }
        }
        __syncthreads();   // prefetch landed (vmcnt) + all waves done reading cur (lgkmcnt)
        cur ^= 1;
    }
    #undef STAGE

    // ---------- phase 2: key table (top-2 over all 64 cts per (row,n)) + serial verify ----------
    int2* sc = (int2*)Xs;   // [64 rows][17 entries] (pad +1)
    #pragma unroll
    for (int r = 0; r < 4; ++r) {
        const int lr = wave * 16 + quad * 4 + r;   // C/D row mapping
        sc[lr * 17 + n] = make_int2(K1[r], K2[r]);
    }
    __syncthreads();

    if (tid < 64) {
        const int row  = tid;
        const int rowg = row0 + row;
        const int2* ent = (const int2*)sc + row * 17;
        int mx = (int)0x80000000;
        #pragma unroll
        for (int e2 = 0; e2 < 16; ++e2) mx = max(mx, ent[e2].x);
        const int thr = mx - BAND_INT;
        int ck[8];
        int nc = 0;
        #pragma unroll
        for (int e2 = 0; e2 < 16; ++e2) {
            const int2 kk = ent[e2];
            if (kk.x >= thr && nc < 8) ck[nc++] = ((kk.x & 63) << 4) | e2;
            if (kk.y >= thr && nc < 8) ck[nc++] = ((kk.y & 63) << 4) | e2;
        }
        float bd = INFINITY;
        int   bk = 0x7fffffff;
        const float4* xr = (const float4*)(x + (size_t)rowg * DIM);
        const float   aq = sAsq[row];
        for (int c = 0; c < nc; ++c) {
            const int k = ck[c];
            const float4* er = (const float4*)(emb + (size_t)k * DIM);
            float acc = 0.0f;
            #pragma unroll 4
            for (int dd = 0; dd < 32; ++dd) {   // sequential d order — matches prior rounds / np
                const float4 xv = xr[dd];
                const float4 ev = er[dd];
                acc += xv.x * ev.x;
                acc += xv.y * ev.y;
                acc += xv.z * ev.z;
                acc += xv.w * ev.w;
            }
            const float t    = aq + Bsq[k];
            const float dist = t - 2.0f * acc;
            if (dist < bd || (dist == bd && k < bk)) { bd = dist; bk = k; }
        }
        sidx[row] = bk;
        atomicAdd(&counts[bk], 1);
        float ss = bd;
        #pragma unroll
        for (int off = 32; off > 0; off >>= 1) ss += __shfl_down(ss, off);
        if (tid == 0) atomicAdd(sse, (double)ss);
    }
    __syncthreads();   // also completes (vmcnt-drains) all counts/sse atomics block-wide

    // ---------- phase 3: fused gather + STE epilogue (64 rows x 32 float4) ----------
    #pragma unroll
    for (int i = tid; i < 2048; i += 256) {
        const int row = i >> 5, d4 = i & 31;
        const int k = sidx[row];
        const float4 xv = *((const float4*)(x + (size_t)(row0 + row) * DIM) + d4);
        const float4 qv = *((const float4*)emb + (size_t)k * 32 + d4);
        float4 ov;
        ov.x = xv.x + (qv.x - xv.x);
        ov.y = xv.y + (qv.y - xv.y);
        ov.z = xv.z + (qv.z - xv.z);
        ov.w = xv.w + (qv.w - xv.w);
        *((float4*)out + (size_t)(row0 + row) * 32 + d4) = ov;
    }

    // ---------- phase 4: last-block-done fused finalize (loss + perplexity) ----------
    // No release fence needed: this block's counts/sse atomics completed at the
    // coherence point before the post-phase-2 barrier released (vmcnt(0) drain).
    if (tid == 0) sIsLast = (atomicAdd(done, 1) == NBLOCKS - 1);
    __syncthreads();
    if (sIsLast) {
        __threadfence();   // acquire (single block, once): invalidate L2 so plain
                           // loads of counts/sse see all other blocks' atomics
        double s = 0.0;
        #pragma unroll
        for (int k = tid; k < 1024; k += 256) {
            const float p = (float)counts[k] * (1.0f / 65536.0f);
            s += (double)p * log((double)p + 1e-10);
        }
        red[tid] = s;
        __syncthreads();
        for (int st = 128; st > 0; st >>= 1) {
            if (tid < st) red[tid] += red[tid + st];
            __syncthreads();
        }
        if (tid == 0) {
            const float m = (float)(*sse * (1.0 / 8388608.0));
            out[NELEMS]     = m + 0.25f * m;
            out[NELEMS + 1] = (float)exp(-red[0]);
        }
    }
}

extern "C" void kernel_launch(void* const* d_in, const int* in_sizes, int n_in,
                              void* d_out, int out_size, void* d_ws, size_t ws_size,
                              hipStream_t stream) {
    const float* x   = (const float*)d_in[0];   // [65536 x 128]
    const float* emb = (const float*)d_in[1];   // [1024 x 128]
    float* out = (float*)d_out;

    char*           ws     = (char*)d_ws;
    float*          Bsq    = (float*)(ws + 0);
    int*            counts = (int*)(ws + 4096);
    double*         sse    = (double*)(ws + 8192);
    int*            done   = (int*)(ws + 12288);
    unsigned short* Ehi    = (unsigned short*)(ws + 16384);

    vq_prep_kernel<<<64, 256, 0, stream>>>(emb, Ehi, Bsq, counts, sse, done);
    vq_main_kernel<<<NBLOCKS, 256, 0, stream>>>(x, emb, Ehi, Bsq, counts, sse, done, out);
}

// Round 7
// 141.772 us; speedup vs baseline: 1.8998x; 1.0274x over previous
//
#include <hip/hip_runtime.h>
#include <cmath>

#define DIM      128
#define NELEMS   8388608
#define BAND_INT 12288   // key band >= 7.3e-4 dot units; approx err sigma ~7e-6, Bsq spread ~2e-5
#define NBLOCKS  1024

typedef __attribute__((ext_vector_type(8))) short  short8;
typedef __attribute__((ext_vector_type(4))) float  f32x4;

// ws layout (bytes):
//   0      : float Bsq[1024]        (4096)
//   4096   : int   counts[1024]     (4096)
//   8192   : double sse             (8)
//   12288  : int   done             (4)
//   16384  : ushort Ehi[131072]     (262144)   -> end 278528

__device__ inline unsigned short f2bf(float x) {
    unsigned u = __float_as_uint(x);
    unsigned r = u + 0x7FFFu + ((u >> 16) & 1u);   // RNE; inputs finite
    return (unsigned short)(r >> 16);
}

// async global->LDS, 16B per lane; LDS dest is wave-uniform base + lane*16
__device__ __forceinline__ void gload_lds16(const void* g, void* l) {
    __builtin_amdgcn_global_load_lds(
        (const __attribute__((address_space(1))) void*)g,
        (__attribute__((address_space(3))) void*)l,
        16, 0, 0);
}

// ---- prep: E -> bf16-hi frags [ct64][kt4][lane64][j8] + Bsq (bit-identical tree) + zero ----
__global__ __launch_bounds__(256) void vq_prep_kernel(
        const float* __restrict__ e, unsigned short* __restrict__ Ehi,
        float* __restrict__ Bsq, int* __restrict__ counts, double* __restrict__ sse,
        int* __restrict__ done) {
    const int tid = threadIdx.x;
    {
        const int t  = blockIdx.x * 256 + tid;   // 0..16383
        const int c  = t >> 4;
        const int gs = t & 15;
        const int kt = gs >> 2, qd = gs & 3;
        const int d0 = gs * 8;
        const float4 v0 = *(const float4*)(e + c * DIM + d0);
        const float4 v1 = *(const float4*)(e + c * DIM + d0 + 4);
        float f[8] = {v0.x, v0.y, v0.z, v0.w, v1.x, v1.y, v1.z, v1.w};
        unsigned short h[8];
        #pragma unroll
        for (int j = 0; j < 8; ++j) h[j] = f2bf(f[j]);
        const int ct = c >> 4, n = c & 15;
        uint4 ph;
        ph.x = h[0] | (h[1] << 16); ph.y = h[2] | (h[3] << 16);
        ph.z = h[4] | (h[5] << 16); ph.w = h[6] | (h[7] << 16);
        *(uint4*)&Ehi[(((ct * 4 + kt) * 64 + qd * 16 + n) * 8)] = ph;
    }
    // Bsq: per-row math bit-identical to round-1 rowsq (float4 squares + 32-lane xor tree)
    {
        const int lane = tid & 31;
        #pragma unroll
        for (int r2 = 0; r2 < 2; ++r2) {
            const int row = blockIdx.x * 16 + (tid >> 5) * 2 + r2;
            const float4 xv = *(const float4*)(e + (size_t)row * DIM + lane * 4);
            float s = xv.x * xv.x + xv.y * xv.y + xv.z * xv.z + xv.w * xv.w;
            #pragma unroll
            for (int off = 16; off > 0; off >>= 1) s += __shfl_xor(s, off);
            if (lane == 0) Bsq[row] = s;
        }
    }
    if (blockIdx.x == 0) {
        ((int4*)counts)[tid] = make_int4(0, 0, 0, 0);
        if (tid == 0) { *sse = 0.0; *done = 0; }
    }
}

// ---- main: LDS-staged shared-B bf16 MFMA scan + exact verify + fused epilogue/finalize ----
// 1024 blocks x 256 thr; block = 64 rows x 1024 codes.
// wave w = row-tile w (rows 16w..16w+15), scans ALL 64 cts in ascending order ->
// per-(row,n) key table = top-2 over 64 cts == round-0 semantics (bit-identical).
// Scan: 4-ct tiles (16 KB) double-buffered in LDS. R6 (2-ct tiles) was MFMA
// dependent-chain latency-bound (R0 vs R6: 2x TLP, same 75 us): per-iteration
// critical path was 2 SEQUENTIAL 4-deep MFMA chains + barrier. 4 cts/tile gives
// 4 INDEPENDENT chains in flight (mutually hide ~20cy dep latency), halves
// barrier count, and doubles prefetch cover.
// NO min-waves clause (R2: forced VGPR=64 spilled 195 MB). NO per-block
// __threadfence() (R4/R5: 1024x buffer_wbl2+buffer_inv kept all 8 XCD-L2s cold,
// +120 us); ordering is guaranteed by the vmcnt(0) drain in __syncthreads.
__global__ __launch_bounds__(256) void vq_main_kernel(
        const float* __restrict__ x, const float* __restrict__ emb,
        const unsigned short* __restrict__ Ehi, const float* __restrict__ Bsq,
        int* __restrict__ counts, double* __restrict__ sse,
        int* __restrict__ done, float* __restrict__ out) {
    // One 32 KB region, three sequential lives:
    //   phase 0: A-hi frags [rg4][kt4][lane64][j8]  (first 16 KB)
    //   scan   : B double-buffer, 2 x (4 cts x 4 KB) = 32 KB
    //   phase 2: sc key table, 64 rows x 17 int2 (8704 B)
    __shared__ __align__(16) unsigned short Xs[16384];
    __shared__ float  sAsq[64];
    __shared__ int    sidx[64];
    __shared__ int    sIsLast;
    __shared__ double red[256];

    const int tid  = threadIdx.x;
    const int wave = tid >> 6;
    const int lane = tid & 63;
    const int n    = lane & 15;
    const int quad = lane >> 4;
    const int row0 = blockIdx.x * 64;

    // ---------- phase 0: stage A-hi frags + bit-exact Asq (prior-round tree) ----------
    {
        const int rl = tid >> 3, tq = tid & 7;    // rl = row 0..31, 8 threads/row
        const int dbase = tq * 16;
        const int rg_lo = rl >> 4, m = rl & 15;
        #pragma unroll
        for (int w = 0; w < 2; ++w) {
            const int r = 32 * w + rl;
            const float* xp = x + (size_t)(row0 + r) * DIM + dbase;
            float p[4];
            #pragma unroll
            for (int q = 0; q < 4; ++q) {
                const float4 v = *(const float4*)(xp + 4 * q);
                p[q] = v.x * v.x + v.y * v.y + v.z * v.z + v.w * v.w;
                const int dd = dbase + 4 * q;
                const int kt = dd >> 5, qd = (dd >> 3) & 3, j = dd & 7;
                unsigned short h0 = f2bf(v.x), h1 = f2bf(v.y), h2 = f2bf(v.z), h3 = f2bf(v.w);
                uint2 ph;
                ph.x = h0 | (h1 << 16); ph.y = h2 | (h3 << 16);
                const int rg = w * 2 + rg_lo;   // == global row >> 4
                *(uint2*)&Xs[(((rg * 4 + kt) * 64 + qd * 16 + m) * 8) + j] = ph;
            }
            // xor-tree levels identical to prior rounds — bit-exact Asq
            #pragma unroll
            for (int q = 0; q < 4; ++q) p[q] += __shfl_xor(p[q], 4);
            #pragma unroll
            for (int q = 0; q < 4; ++q) p[q] += __shfl_xor(p[q], 2);
            #pragma unroll
            for (int q = 0; q < 4; ++q) p[q] += __shfl_xor(p[q], 1);
            const float s = (p[0] + p[2]) + (p[1] + p[3]);
            if (tq == 0) sAsq[r] = s;
        }
    }
    __syncthreads();

    short8 Af[4];        // this wave's single row-tile: rg = wave
    #pragma unroll
    for (int kt = 0; kt < 4; ++kt)
        Af[kt] = *(const short8*)&Xs[(((wave * 4 + kt) * 64 + lane) * 8)];
    __syncthreads();     // all frag reads done before Xs becomes the B staging buffer

    // ---------- phase 1: LDS-staged scan over all 64 cts, 4 cts/tile, dbuf ----------
    int K1[4], K2[4];
    #pragma unroll
    for (int i = 0; i < 4; ++i) { K1[i] = (int)0x80000000; K2[i] = (int)0x80000000; }

    const f32x4 cinit = {1.0f, 1.0f, 1.0f, 1.0f};   // +1.0 bias -> positive, int-monotone keys

    // wave w stages bytes [4096w, 4096w+4096) of each 16 KB tile (4 calls x 1 KB)
    #define STAGE(CUR, IT)                                                                \
        do {                                                                              \
            const char* _g = (const char*)Ehi + (size_t)(IT) * 16384 + wave * 4096 + lane * 16; \
            char*       _l = (char*)Xs + (CUR) * 16384 + wave * 4096;                     \
            gload_lds16(_g,        _l);                                                   \
            gload_lds16(_g + 1024, _l + 1024);                                            \
            gload_lds16(_g + 2048, _l + 2048);                                            \
            gload_lds16(_g + 3072, _l + 3072);                                            \
        } while (0)

    int cur = 0;
    STAGE(0, 0);
    __syncthreads();     // drains staging vmcnt; tile 0 visible to all waves
    for (int it = 0; it < 16; ++it) {
        if (it < 15) STAGE(cur ^ 1, it + 1);   // async prefetch next tile
        // 4 independent MFMA chains (one per ct) — unrolled so LLVM interleaves them
        #pragma unroll
        for (int c = 0; c < 4; ++c) {
            const int ct = 4 * it + c;         // cts ascending 0..63 — same order as R0
            short8 Bf[4];
            #pragma unroll
            for (int kt = 0; kt < 4; ++kt)
                Bf[kt] = *(const short8*)&Xs[(size_t)cur * 8192 + c * 2048 + (kt * 64 + lane) * 8];
            f32x4 a = cinit;
            #pragma unroll
            for (int kt = 0; kt < 4; ++kt)
                a = __builtin_amdgcn_mfma_f32_16x16x32_bf16(Af[kt], Bf[kt], a, 0, 0, 0);
            #pragma unroll
            for (int r = 0; r < 4; ++r) {
                const int k0 = (__float_as_int(a[r]) & (int)0xFFFFFFC0) | ct;
                const int t0 = min(K1[r], k0);
                K1[r] = max(K1[r], k0);
                K2[r] = max(K2[r], t0);
            }
        }
        __syncthreads();   // prefetch landed (vmcnt) + all waves done reading cur (lgkmcnt)
        cur ^= 1;
    }
    #undef STAGE

    // ---------- phase 2: key table (top-2 over all 64 cts per (row,n)) + serial verify ----------
    int2* sc = (int2*)Xs;   // [64 rows][17 entries] (pad +1)
    #pragma unroll
    for (int r = 0; r < 4; ++r) {
        const int lr = wave * 16 + quad * 4 + r;   // C/D row mapping
        sc[lr * 17 + n] = make_int2(K1[r], K2[r]);
    }
    __syncthreads();

    if (tid < 64) {
        const int row  = tid;
        const int rowg = row0 + row;
        const int2* ent = (const int2*)sc + row * 17;
        int mx = (int)0x80000000;
        #pragma unroll
        for (int e2 = 0; e2 < 16; ++e2) mx = max(mx, ent[e2].x);
        const int thr = mx - BAND_INT;
        int ck[8];
        int nc = 0;
        #pragma unroll
        for (int e2 = 0; e2 < 16; ++e2) {
            const int2 kk = ent[e2];
            if (kk.x >= thr && nc < 8) ck[nc++] = ((kk.x & 63) << 4) | e2;
            if (kk.y >= thr && nc < 8) ck[nc++] = ((kk.y & 63) << 4) | e2;
        }
        float bd = INFINITY;
        int   bk = 0x7fffffff;
        const float4* xr = (const float4*)(x + (size_t)rowg * DIM);
        const float   aq = sAsq[row];
        for (int c = 0; c < nc; ++c) {
            const int k = ck[c];
            const float4* er = (const float4*)(emb + (size_t)k * DIM);
            float acc = 0.0f;
            #pragma unroll 4
            for (int dd = 0; dd < 32; ++dd) {   // sequential d order — matches prior rounds / np
                const float4 xv = xr[dd];
                const float4 ev = er[dd];
                acc += xv.x * ev.x;
                acc += xv.y * ev.y;
                acc += xv.z * ev.z;
                acc += xv.w * ev.w;
            }
            const float t    = aq + Bsq[k];
            const float dist = t - 2.0f * acc;
            if (dist < bd || (dist == bd && k < bk)) { bd = dist; bk = k; }
        }
        sidx[row] = bk;
        atomicAdd(&counts[bk], 1);
        float ss = bd;
        #pragma unroll
        for (int off = 32; off > 0; off >>= 1) ss += __shfl_down(ss, off);
        if (tid == 0) atomicAdd(sse, (double)ss);
    }
    __syncthreads();   // also completes (vmcnt-drains) all counts/sse atomics block-wide

    // ---------- phase 3: fused gather + STE epilogue (64 rows x 32 float4) ----------
    #pragma unroll
    for (int i = tid; i < 2048; i += 256) {
        const int row = i >> 5, d4 = i & 31;
        const int k = sidx[row];
        const float4 xv = *((const float4*)(x + (size_t)(row0 + row) * DIM) + d4);
        const float4 qv = *((const float4*)emb + (size_t)k * 32 + d4);
        float4 ov;
        ov.x = xv.x + (qv.x - xv.x);
        ov.y = xv.y + (qv.y - xv.y);
        ov.z = xv.z + (qv.z - xv.z);
        ov.w = xv.w + (qv.w - xv.w);
        *((float4*)out + (size_t)(row0 + row) * 32 + d4) = ov;
    }

    // ---------- phase 4: last-block-done fused finalize (loss + perplexity) ----------
    // No release fence needed: this block's counts/sse atomics completed at the
    // coherence point before the post-phase-2 barrier released (vmcnt(0) drain).
    if (tid == 0) sIsLast = (atomicAdd(done, 1) == NBLOCKS - 1);
    __syncthreads();
    if (sIsLast) {
        __threadfence();   // acquire (single block, once): invalidate L2 so plain
                           // loads of counts/sse see all other blocks' atomics
        double s = 0.0;
        #pragma unroll
        for (int k = tid; k < 1024; k += 256) {
            const float p = (float)counts[k] * (1.0f / 65536.0f);
            s += (double)p * log((double)p + 1e-10);
        }
        red[tid] = s;
        __syncthreads();
        for (int st = 128; st > 0; st >>= 1) {
            if (tid < st) red[tid] += red[tid + st];
            __syncthreads();
        }
        if (tid == 0) {
            const float m = (float)(*sse * (1.0 / 8388608.0));
            out[NELEMS]     = m + 0.25f * m;
            out[NELEMS + 1] = (float)exp(-red[0]);
        }
    }
}

extern "C" void kernel_launch(void* const* d_in, const int* in_sizes, int n_in,
                              void* d_out, int out_size, void* d_ws, size_t ws_size,
                              hipStream_t stream) {
    const float* x   = (const float*)d_in[0];   // [65536 x 128]
    const float* emb = (const float*)d_in[1];   // [1024 x 128]
    float* out = (float*)d_out;

    char*           ws     = (char*)d_ws;
    float*          Bsq    = (float*)(ws + 0);
    int*            counts = (int*)(ws + 4096);
    double*         sse    = (double*)(ws + 8192);
    int*            done   = (int*)(ws + 12288);
    unsigned short* Ehi    = (unsigned short*)(ws + 16384);

    vq_prep_kernel<<<64, 256, 0, stream>>>(emb, Ehi, Bsq, counts, sse, done);
    vq_main_kernel<<<NBLOCKS, 256, 0, stream>>>(x, emb, Ehi, Bsq, counts, sse, done, out);
}